// Round 1
// baseline (1061.199 us; speedup 1.0000x reference)
//
#include <hip/hip_runtime.h>

#define B_ 32
#define C_ 512
#define N_ 4096
#define T_ 72
#define K_ 64
#define EPSF 1e-12f

// ---------------------------------------------------------------------------
// Reduction helper: full block (256 thr) sum; result valid on thread 0 only.
// ---------------------------------------------------------------------------
__device__ __forceinline__ float block_reduce_sum_256(float v) {
    #pragma unroll
    for (int o = 32; o > 0; o >>= 1) v += __shfl_down(v, o, 64);
    __shared__ float w[4];
    const int lane = threadIdx.x & 63, wid = threadIdx.x >> 6;
    if (lane == 0) w[wid] = v;
    __syncthreads();
    float r = 0.f;
    if (threadIdx.x == 0) r = w[0] + w[1] + w[2] + w[3];
    return r;
}

// ---------------------------------------------------------------------------
// Kernel 1: per-(b,n) channel L2 norm, logits (72), softmax, store assign k<64.
// grid (N/256, B), block 256. One thread per n.
// k-loops fully unrolled -> logits[] lives in VGPRs; conv_w index is
// wave-uniform -> scalar loads on the sQC pipe.
// ---------------------------------------------------------------------------
__global__ __launch_bounds__(256) void k_norm_assign(
    const float* __restrict__ x, const float* __restrict__ conv_w,
    const float* __restrict__ conv_b,
    float* __restrict__ assign, float* __restrict__ inv_norm)
{
    const int n = blockIdx.x * 256 + threadIdx.x;
    const int b = blockIdx.y;
    const float* xb = x + (size_t)b * C_ * N_ + n;

    // pass 1: sum of squares over channels (coalesced across threads)
    float ss = 0.f;
    #pragma unroll 8
    for (int c = 0; c < C_; ++c) {
        float v = xb[(size_t)c * N_];
        ss = fmaf(v, v, ss);
    }
    const float inv = 1.0f / fmaxf(sqrtf(ss), EPSF);
    inv_norm[(size_t)b * N_ + n] = inv;

    // pass 2: logits = conv_w @ xn + conv_b
    float logits[T_];
    #pragma unroll
    for (int k = 0; k < T_; ++k) logits[k] = conv_b[k];

    #pragma unroll 2
    for (int c = 0; c < C_; ++c) {
        const float xv = xb[(size_t)c * N_] * inv;
        #pragma unroll
        for (int k = 0; k < T_; ++k)
            logits[k] = fmaf(conv_w[k * C_ + c], xv, logits[k]);
    }

    // softmax over 72 clusters
    float m = logits[0];
    #pragma unroll
    for (int k = 1; k < T_; ++k) m = fmaxf(m, logits[k]);
    float s = 0.f;
    #pragma unroll
    for (int k = 0; k < T_; ++k) {
        logits[k] = expf(logits[k] - m);
        s += logits[k];
    }
    const float rs = 1.0f / s;

    // store soft-assignments for real clusters only (ghosts feed only the
    // softmax denominator and ops that cancel under the final L2 norms)
    float* ab = assign + (size_t)b * K_ * N_ + n;
    #pragma unroll
    for (int k = 0; k < K_; ++k) ab[(size_t)k * N_] = logits[k] * rs;
}

// ---------------------------------------------------------------------------
// Kernel 2: mass[b,k] = sum_n assign[b,k,n].  grid (K, B), block 256.
// ---------------------------------------------------------------------------
__global__ __launch_bounds__(256) void k_mass(
    const float* __restrict__ assign, float* __restrict__ mass)
{
    const int k = blockIdx.x, b = blockIdx.y;
    const float* p = assign + ((size_t)b * K_ + k) * N_;
    float s = 0.f;
    for (int i = threadIdx.x; i < N_; i += 256) s += p[i];
    const float tot = block_reduce_sum_256(s);
    if (threadIdx.x == 0) mass[b * K_ + k] = tot;
}

// ---------------------------------------------------------------------------
// Kernel 3: agg[b,k,c] = sum_n assign[b,k,n] * x[b,c,n] * inv_norm[b,n];
//           vlad = agg - centroid[k,c]*mass[b,k]  -> written to d_out.
// grid (C/64, B), block 256 (16x16 thread tile, 4x4 acc each).
// LDS pitch 65 -> staging writes stride-1, compute reads broadcast/2-way.
// ---------------------------------------------------------------------------
#define TN 64
__global__ __launch_bounds__(256) void k_agg(
    const float* __restrict__ x, const float* __restrict__ assign,
    const float* __restrict__ inv_norm, const float* __restrict__ centroids,
    const float* __restrict__ mass, float* __restrict__ out)
{
    __shared__ float lds_a[K_][TN + 1];
    __shared__ float lds_x[TN][TN + 1];

    const int b  = blockIdx.y;
    const int c0 = blockIdx.x * TN;
    const int tid = threadIdx.x;
    const int ti = tid >> 4, tj = tid & 15;

    const float* ab = assign   + (size_t)b * K_ * N_;
    const float* xb = x        + (size_t)b * C_ * N_;
    const float* ib = inv_norm + (size_t)b * N_;

    float acc[4][4] = {};

    for (int n0 = 0; n0 < N_; n0 += TN) {
        __syncthreads();
        #pragma unroll
        for (int i = 0; i < 16; ++i) {
            const int idx = tid + i * 256;          // 0..4095
            const int r = idx >> 6, nn = idx & 63;
            lds_a[r][nn] = ab[(size_t)r * N_ + n0 + nn];
            lds_x[r][nn] = xb[(size_t)(c0 + r) * N_ + n0 + nn] * ib[n0 + nn];
        }
        __syncthreads();

        #pragma unroll 4
        for (int nn = 0; nn < TN; ++nn) {
            float av[4], xv[4];
            #pragma unroll
            for (int i = 0; i < 4; ++i) av[i] = lds_a[ti * 4 + i][nn];
            #pragma unroll
            for (int j = 0; j < 4; ++j) xv[j] = lds_x[tj * 4 + j][nn];
            #pragma unroll
            for (int i = 0; i < 4; ++i)
                #pragma unroll
                for (int j = 0; j < 4; ++j)
                    acc[i][j] = fmaf(av[i], xv[j], acc[i][j]);
        }
    }

    // epilogue: vlad = agg - centroid*mass, write to out (== vlad buffer)
    #pragma unroll
    for (int i = 0; i < 4; ++i) {
        const int k = ti * 4 + i;
        const float mk = mass[b * K_ + k];
        #pragma unroll
        for (int j = 0; j < 4; ++j) {
            const int c = c0 + tj * 4 + j;
            acc[i][j] = fmaf(-centroids[k * C_ + c], mk, acc[i][j]);
        }
        float4 v = make_float4(acc[i][0], acc[i][1], acc[i][2], acc[i][3]);
        *(float4*)(out + (size_t)b * (K_ * C_) + (size_t)k * C_ + c0 + tj * 4) = v;
    }
}

// ---------------------------------------------------------------------------
// Kernel 4: per-(b,k) row norm of vlad; accumulate global sumsq of the
// row-normalized values into gsum[b].  grid (K, B), block 256.
// ---------------------------------------------------------------------------
__global__ __launch_bounds__(256) void k_rnorm(
    const float* __restrict__ vlad, float* __restrict__ rnorm,
    float* __restrict__ gsum)
{
    const int k = blockIdx.x, b = blockIdx.y;
    const float* p = vlad + ((size_t)b * K_ + k) * C_;
    float s = 0.f;
    for (int i = threadIdx.x; i < C_; i += 256) {
        float v = p[i];
        s = fmaf(v, v, s);
    }
    const float ss = block_reduce_sum_256(s);
    if (threadIdx.x == 0) {
        const float rn = fmaxf(sqrtf(ss), EPSF);
        rnorm[b * K_ + k] = rn;
        atomicAdd(gsum + b, ss / (rn * rn));
    }
}

// ---------------------------------------------------------------------------
// Kernel 5: out = vlad / rnorm[b,k] / gnorm[b], in place, float4.
// grid: (B*K*C/4)/256 blocks.
// ---------------------------------------------------------------------------
__global__ __launch_bounds__(256) void k_final(
    float* __restrict__ out, const float* __restrict__ rnorm,
    const float* __restrict__ gsum)
{
    const size_t t  = (size_t)blockIdx.x * 256 + threadIdx.x;
    const size_t i4 = t * 4;
    const int b = (int)(i4 >> 15);           // 64*512 per batch
    const int k = (int)((i4 >> 9) & 63);     // 512 per cluster
    const float gn = fmaxf(sqrtf(gsum[b]), EPSF);
    const float sc = 1.0f / (rnorm[b * K_ + k] * gn);
    float4 v = *(const float4*)(out + i4);
    v.x *= sc; v.y *= sc; v.z *= sc; v.w *= sc;
    *(float4*)(out + i4) = v;
}

// ---------------------------------------------------------------------------
extern "C" void kernel_launch(void* const* d_in, const int* in_sizes, int n_in,
                              void* d_out, int out_size, void* d_ws, size_t ws_size,
                              hipStream_t stream) {
    const float* x         = (const float*)d_in[0];
    const float* centroids = (const float*)d_in[1];
    const float* conv_w    = (const float*)d_in[2];
    const float* conv_b    = (const float*)d_in[3];
    // d_in[4..8] = ghost_weights, w1, b1, w2, b2: provably no effect on the
    // output (positive per-row scalars cancel inside the intra-cluster L2
    // normalization; ghost rows are dropped) -> unused.

    float* out = (float*)d_out;
    float* ws  = (float*)d_ws;

    float* assign   = ws;                                   // B*K*N
    float* inv_norm = assign + (size_t)B_ * K_ * N_;        // B*N
    float* mass     = inv_norm + (size_t)B_ * N_;           // B*K
    float* rnorm    = mass + B_ * K_;                       // B*K
    float* gsum     = rnorm + B_ * K_;                      // B

    hipMemsetAsync(gsum, 0, B_ * sizeof(float), stream);

    k_norm_assign<<<dim3(N_ / 256, B_), 256, 0, stream>>>(x, conv_w, conv_b,
                                                          assign, inv_norm);
    k_mass<<<dim3(K_, B_), 256, 0, stream>>>(assign, mass);
    k_agg<<<dim3(C_ / TN, B_), 256, 0, stream>>>(x, assign, inv_norm,
                                                 centroids, mass, out);
    k_rnorm<<<dim3(K_, B_), 256, 0, stream>>>(out, rnorm, gsum);
    k_final<<<(out_size / 4 + 255) / 256, 256, 0, stream>>>(out, rnorm, gsum);
}